// Round 14
// baseline (388.947 us; speedup 1.0000x reference)
//
#include <hip/hip_runtime.h>

#define B_ 512
#define T_ 256
#define F_ 8
#define H_ 128
#define BT_ (B_*T_)
#define MH_ 512
#define L2E 1.4426950408889634f

typedef __attribute__((ext_vector_type(4))) float f32x4;
typedef __attribute__((ext_vector_type(8))) __bf16 bf16x8;

// Static device scratch
// g_w2t: W2^T bf16, row n holds k-elems PRE-SWIZZLED: elem (k ^ ((n&7)<<3)).
__device__ unsigned short g_w2t[MH_*MH_];
// packed Whh/Wih bf16, [head][pc][k], PRE-SCALED: i,f,o rows by -log2e, g rows by +2log2e
__device__ unsigned short g_whh[3][512][128];
__device__ unsigned short g_wih[3][512][32];
__device__ unsigned short g_xbf[3][B_*T_*F_];        // x in bf16, same (B,T,F) layout

__device__ __forceinline__ unsigned short f2bf(float f){
  unsigned int u = __float_as_uint(f);
  unsigned int r = (u + 0x7FFFu + ((u >> 16) & 1u)) >> 16;  // RNE
  return (unsigned short)r;
}

#if __has_builtin(__builtin_amdgcn_exp2f)
#define EXP2F __builtin_amdgcn_exp2f
#else
#define EXP2F exp2f
#endif
#define RCPF __builtin_amdgcn_rcpf

// DPP-based partial-sum step on the VALU pipe (verified +46us in r12).
template<int CTRL>
__device__ __forceinline__ float dpp_sum_step(float v){
  int t = __builtin_amdgcn_update_dpp(0, __float_as_int(v), CTRL, 0xF, 0xF, true);
  return v + __int_as_float(t);
}

struct LstmArgs {
  const float* x[3];
  const float* Wih[3];
  const float* Whh[3];
  const float* bias[3];
  const float* hw[3];
  const float* hb[3];
  float* out;
};

// One fused prep: W2^T pack (pre-swizzled) + Whh/Wih MFMA-order pack
// (pre-scaled by +-log2e) + x to bf16.
__global__ __launch_bounds__(256) void prep_all(LstmArgs A, const float* __restrict__ W2){
  const int NW2 = MH_*MH_;
  const int NW  = 3*512*128;
  const int NI  = 3*512*32;
  const int NX  = 3*B_*T_*F_;
  const int TOT = NW2 + NW + NI + NX;
  for (int i = blockIdx.x*256 + threadIdx.x; i < TOT; i += gridDim.x*256){
    if (i < NW2){
      int n = i >> 9;
      int k = i & 511;
      g_w2t[(n << 9) | (k ^ ((n & 7) << 3))] = f2bf(W2[(size_t)k * MH_ + n]);
    } else if (i < NW2 + NW){
      int j = i - NW2;
      int head = j >> 16;
      int r = j & 65535;
      int pc = r >> 7, k = r & 127;
      int w = pc >> 6, g = (pc >> 4) & 3, s = pc & 15;
      int row = g*128 + w*16 + s;
      float sc = (g == 2) ? (2.0f*L2E) : (-L2E);
      g_whh[head][pc][k] = f2bf(A.Whh[head][row*H_ + k] * sc);
    } else if (i < NW2 + NW + NI){
      int j = i - NW2 - NW;
      int head = j >> 14;
      int r = j & 16383;
      int pc = r >> 5, k = r & 31;
      int w = pc >> 6, g = (pc >> 4) & 3, s = pc & 15;
      int row = g*128 + w*16 + s;
      float sc = (g == 2) ? (2.0f*L2E) : (-L2E);
      g_wih[head][pc][k] = (k < 8) ? f2bf(A.Wih[head][row*F_ + k] * sc) : (unsigned short)0;
    } else {
      int j = i - NW2 - NW - NI;
      int head = j >> 20;
      int r = j & 1048575;
      g_xbf[head][r] = f2bf(A.x[head][r]);
    }
  }
}

// MFMA LSTM: round-12 verified structure (DPP sums, per-step rotating finalize,
// plain __syncthreads, part[2] double-buffer) with 4-BATCH tiles / 384 blocks:
//  batch b (0..3) lives at A/C row 4b -> each lane owns C reg r=0 only
//  => 1 cell/lane (halves cell VALU/TRANS), and 384 blocks puts 2 independent
//  barrier groups on 128 CUs (cross-group latency hiding; 0 idle CUs).
__global__ __launch_bounds__(512) void lstm_mfma_kernel(LstmArgs A){
  const int head   = blockIdx.x >> 7;          // 128 tiles per head, 384 blocks
  const int batch0 = (blockIdx.x & 127) * 4;
  const int tid = threadIdx.x;
  const int w   = tid >> 6;
  const int l   = tid & 63;
  const int c16 = l & 15;
  const int kb  = (l >> 4) * 8;

  const float* __restrict__ bs  = A.bias[head];
  const float* __restrict__ hwp = A.hw[head];
  const float hbv = A.hb[head][0];
  float* __restrict__ D = A.out + (size_t)head * BT_;

  // register-resident B-fragments
  bf16x8 bh[4][4];
  bf16x8 bx[4];
  #pragma unroll
  for (int g = 0; g < 4; ++g){
    const int pc = w*64 + g*16 + c16;
    #pragma unroll
    for (int kk = 0; kk < 4; ++kk)
      bh[g][kk] = *(const bf16x8*)&g_whh[head][pc][kk*32 + kb];
    bx[g] = *(const bf16x8*)&g_wih[head][pc][kb];
  }

  const int u = w*16 + c16;
  const float bi_ = bs[u]        * (-L2E);
  const float bf_ = bs[H_+u]     * (-L2E);
  const float bg_ = bs[2*H_+u]   * (2.0f*L2E);
  const float bo_ = bs[3*H_+u]   * (-L2E);
  const float hw_u = hwp[u];

  __shared__ __align__(16) unsigned short h_bf[2][16][132];
  __shared__ float part[2][4][8];

  for (int i = tid; i < 2*16*132; i += 512) ((unsigned short*)h_bf)[i] = 0;

  float cst = 0.f;
  float pp  = 0.f;

  // x A-row mapping: lane c16 supplies A-row c16; valid rows {0,4,8,12}
  const int bt = c16 >> 2;                     // batch-in-tile for row c16
  const bool xvalid = (l < 16) && ((l & 3) == 0);
  const unsigned short* __restrict__ xrow =
      &g_xbf[head][(size_t)(batch0 + bt) * (T_*F_)];

  bf16x8 ax_cur = {};
  if (xvalid) ax_cur = *(const bf16x8*)(xrow);

  __syncthreads();

  int cur = 0;
  for (int ts = 0; ts < T_; ++ts){
    // A-frags for current h
    bf16x8 ah[4];
    #pragma unroll
    for (int kk = 0; kk < 4; ++kk)
      ah[kk] = *(const bf16x8*)&h_bf[cur][c16][kk*32 + kb];

    // prefetch next step's x (off the critical path)
    bf16x8 ax_nxt = {};
    {
      const int tn = (ts + 1 < T_) ? ts + 1 : ts;
      if (xvalid) ax_nxt = *(const bf16x8*)(xrow + tn*F_);
    }

    // h-MFMAs first (zero init), x-MFMA last
    f32x4 acc[4];
    const f32x4 z4 = {0.f, 0.f, 0.f, 0.f};
    #pragma unroll
    for (int g = 0; g < 4; ++g)
      acc[g] = __builtin_amdgcn_mfma_f32_16x16x32_bf16(ah[0], bh[g][0], z4, 0, 0, 0);
    #pragma unroll
    for (int kk = 1; kk < 4; ++kk){
      #pragma unroll
      for (int g = 0; g < 4; ++g)
        acc[g] = __builtin_amdgcn_mfma_f32_16x16x32_bf16(ah[kk], bh[g][kk], acc[g], 0, 0, 0);
    }
    #pragma unroll
    for (int g = 0; g < 4; ++g)
      acc[g] = __builtin_amdgcn_mfma_f32_16x16x32_bf16(ax_cur, bx[g], acc[g], 0, 0, 0);

    // previous step's head-dot reduction (DPP on VALU; overlaps MFMA)
    if (ts > 0){
      float v = pp;
      v = dpp_sum_step<0xB1>(v);    // ~xor1
      v = dpp_sum_step<0x4E>(v);    // ~xor2
      v = dpp_sum_step<0x141>(v);   // half-mirror (complementary quads)
      v = dpp_sum_step<0x140>(v);   // mirror (complementary octets)
      if (c16 == 0) part[(ts-1) & 1][l >> 4][w] = v;
    }

    // cell update: 1 cell/lane (reg r=0), exp2-form gates
    {
      const float Zi = acc[0][0] + bi_;
      const float Zf = acc[1][0] + bf_;
      const float Zg = acc[2][0] + bg_;
      const float Zo = acc[3][0] + bo_;
      const float si = RCPF(1.f + EXP2F(Zi));
      const float sf = RCPF(1.f + EXP2F(Zf));
      const float tg = 1.f - 2.f * RCPF(EXP2F(Zg) + 1.f);
      const float so = RCPF(1.f + EXP2F(Zo));
      cst = sf * cst + si * tg;
      const float tc = 1.f - 2.f * RCPF(EXP2F(cst * (2.0f*L2E)) + 1.f);
      const float hnr = so * tc;
      h_bf[cur ^ 1][(l >> 4)*4][u] = f2bf(hnr);
      pp = hnr * hw_u;                       // consumed next iteration
    }

    __syncthreads();                         // new h + part visible

    // finalize D for step ts-1 (rotating wave, lanes 0-31; overlaps next step)
    if (ts > 0 && w == (ts & 7) && l < 32){
      const int b  = l >> 3;
      const int wv = l & 7;
      float v = part[(ts-1) & 1][b][wv];
      v = dpp_sum_step<0xB1>(v);
      v = dpp_sum_step<0x4E>(v);
      v = dpp_sum_step<0x141>(v);
      if (wv == 0) D[(size_t)(batch0 + b) * T_ + (ts-1)] = v + hbv;
    }

    ax_cur = ax_nxt;
    cur ^= 1;
  }

  // epilogue: step T-1's head-dot
  {
    float v = pp;
    v = dpp_sum_step<0xB1>(v);
    v = dpp_sum_step<0x4E>(v);
    v = dpp_sum_step<0x141>(v);
    v = dpp_sum_step<0x140>(v);
    if (c16 == 0) part[(T_-1) & 1][l >> 4][w] = v;
  }
  __syncthreads();
  if (tid < 32){
    const int b  = tid >> 3;
    const int wv = tid & 7;
    float v = part[(T_-1) & 1][b][wv];
    v = dpp_sum_step<0xB1>(v);
    v = dpp_sum_step<0x4E>(v);
    v = dpp_sum_step<0x141>(v);
    if (wv == 0) D[(size_t)(batch0 + b) * T_ + (T_-1)] = v + hbv;
  }
}

// Fused MLP v3 (verified ~50us): 256 threads, 128 rows/block, grid 1024,
// launch_bounds(256,2). afr computed once. Full N in 16 passes of 32 cols;
// W2 slice double-buffered in LDS. Unchanged from round 12.
__global__ __launch_bounds__(256, 2) void mlp_kernel(
    const float* __restrict__ Dbase,
    const float* __restrict__ W1, const float* __restrict__ b1,
    const float* __restrict__ b2, const float* __restrict__ W3,
    const float* __restrict__ b3, float* __restrict__ out)
{
  __shared__ __align__(16) unsigned short buf[2][32*512];   // 2 x 32KB

  const int tid = threadIdx.x;
  const int l   = tid & 63;
  const int c16 = l & 15;
  const int kb  = (l >> 4) * 8;
  const int w   = tid >> 6;                 // 0..3
  const int m0  = blockIdx.x * 128 + w * 32;

  // A fragments for 2 M-tiles (computed once; live for whole kernel)
  bf16x8 afr[2][16];
  {
    float d[2][3];
    #pragma unroll
    for (int mt = 0; mt < 2; ++mt){
      const int gr = m0 + mt*16 + c16;
      d[mt][0] = Dbase[gr];
      d[mt][1] = Dbase[BT_ + gr];
      d[mt][2] = Dbase[2*BT_ + gr];
    }
    #pragma unroll
    for (int ks = 0; ks < 16; ++ks){
      const int kg = ks*32 + kb;
      const f32x4 wa0 = *(const f32x4*)(W1 + kg);          const f32x4 wa1 = *(const f32x4*)(W1 + kg + 4);
      const f32x4 wb0 = *(const f32x4*)(W1 + MH_ + kg);    const f32x4 wb1 = *(const f32x4*)(W1 + MH_ + kg + 4);
      const f32x4 wc0 = *(const f32x4*)(W1 + 2*MH_ + kg);  const f32x4 wc1 = *(const f32x4*)(W1 + 2*MH_ + kg + 4);
      const f32x4 bv0 = *(const f32x4*)(b1 + kg);          const f32x4 bv1 = *(const f32x4*)(b1 + kg + 4);
      #pragma unroll
      for (int mt = 0; mt < 2; ++mt){
        union { unsigned short us[8]; bf16x8 v; } au;
        #pragma unroll
        for (int i = 0; i < 4; ++i){
          float v0 = fmaf(d[mt][2], wc0[i], fmaf(d[mt][1], wb0[i], fmaf(d[mt][0], wa0[i], bv0[i])));
          float v1 = fmaf(d[mt][2], wc1[i], fmaf(d[mt][1], wb1[i], fmaf(d[mt][0], wa1[i], bv1[i])));
          au.us[i]     = f2bf(fmaxf(v0, 0.f));
          au.us[4 + i] = f2bf(fmaxf(v1, 0.f));
        }
        afr[mt][ks] = au.v;
      }
    }
  }

  // prologue: stage regs for pass 0 (pass = 32 cols = 2048 uint4; 8/thread)
  const uint4* __restrict__ gsrc = (const uint4*)g_w2t;
  uint4 rg0, rg1, rg2, rg3, rg4, rg5, rg6, rg7;
  {
    const uint4* s = gsrc + tid;
    rg0 = s[0*256]; rg1 = s[1*256]; rg2 = s[2*256]; rg3 = s[3*256];
    rg4 = s[4*256]; rg5 = s[5*256]; rg6 = s[6*256]; rg7 = s[7*256];
  }

  float rs[2][4] = {{0.f,0.f,0.f,0.f},{0.f,0.f,0.f,0.f}};

  #pragma unroll 1
  for (int p = 0; p < 16; ++p){
    {
      uint4* bw = (uint4*)buf[p & 1] + tid;
      bw[0*256] = rg0; bw[1*256] = rg1; bw[2*256] = rg2; bw[3*256] = rg3;
      bw[4*256] = rg4; bw[5*256] = rg5; bw[6*256] = rg6; bw[7*256] = rg7;
    }
    __syncthreads();               // write visible; dbuf makes this the ONLY barrier
    if (p < 15){
      const uint4* s = gsrc + (p + 1) * 2048 + tid;
      rg0 = s[0*256]; rg1 = s[1*256]; rg2 = s[2*256]; rg3 = s[3*256];
      rg4 = s[4*256]; rg5 = s[5*256]; rg6 = s[6*256]; rg7 = s[7*256];
    }
    float b2v[2], w3v[2];
    #pragma unroll
    for (int nt = 0; nt < 2; ++nt){
      const int n = p*32 + nt*16 + c16;
      b2v[nt] = b2[n];
      w3v[nt] = W3[n];
    }

    const unsigned short* __restrict__ bb = buf[p & 1];
    f32x4 acc[2][2];
    #pragma unroll
    for (int nt = 0; nt < 2; ++nt){
      f32x4 z = {0.f,0.f,0.f,0.f};
      acc[0][nt] = z; acc[1][nt] = z;
    }
    #pragma unroll
    for (int ks = 0; ks < 16; ++ks){
      #pragma unroll
      for (int nt = 0; nt < 2; ++nt){
        const int nl = nt*16 + c16;                    // local col 0..31
        const bf16x8 bfr =
          *(const bf16x8*)&bb[(nl << 9) | ((ks*32 + kb) ^ ((nl & 7) << 3))];
        acc[0][nt] = __builtin_amdgcn_mfma_f32_16x16x32_bf16(afr[0][ks], bfr, acc[0][nt], 0, 0, 0);
        acc[1][nt] = __builtin_amdgcn_mfma_f32_16x16x32_bf16(afr[1][ks], bfr, acc[1][nt], 0, 0, 0);
      }
    }
    #pragma unroll
    for (int nt = 0; nt < 2; ++nt){
      #pragma unroll
      for (int mt = 0; mt < 2; ++mt)
        #pragma unroll
        for (int r = 0; r < 4; ++r)
          rs[mt][r] += fmaxf(acc[mt][nt][r] + b2v[nt], 0.f) * w3v[nt];
    }
  }

  // reduce across the 16 lanes (c16 bits) sharing the same C-rows
  #pragma unroll
  for (int mt = 0; mt < 2; ++mt){
    #pragma unroll
    for (int r = 0; r < 4; ++r){
      rs[mt][r] += __shfl_xor(rs[mt][r], 1);
      rs[mt][r] += __shfl_xor(rs[mt][r], 2);
      rs[mt][r] += __shfl_xor(rs[mt][r], 4);
      rs[mt][r] += __shfl_xor(rs[mt][r], 8);
    }
  }
  if (c16 == 0){
    const float bv = b3[0];
    #pragma unroll
    for (int mt = 0; mt < 2; ++mt){
      const int row = m0 + mt*16 + (l >> 4) * 4;
      #pragma unroll
      for (int r = 0; r < 4; ++r)
        out[3*BT_ + row + r] = rs[mt][r] + bv;
    }
  }
}

extern "C" void kernel_launch(void* const* d_in, const int* in_sizes, int n_in,
                              void* d_out, int out_size, void* d_ws, size_t ws_size,
                              hipStream_t stream){
  LstmArgs A;
  for (int i = 0; i < 3; ++i){
    A.x[i]    = (const float*)d_in[i];
    A.Wih[i]  = (const float*)d_in[3 + i*5 + 0];
    A.Whh[i]  = (const float*)d_in[3 + i*5 + 1];
    A.bias[i] = (const float*)d_in[3 + i*5 + 2];
    A.hw[i]   = (const float*)d_in[3 + i*5 + 3];
    A.hb[i]   = (const float*)d_in[3 + i*5 + 4];
  }
  A.out = (float*)d_out;

  prep_all<<<dim3(2048), dim3(256), 0, stream>>>(A, (const float*)d_in[20]);
  lstm_mfma_kernel<<<dim3(384), dim3(512), 0, stream>>>(A);
  mlp_kernel<<<dim3(1024), dim3(256), 0, stream>>>((const float*)d_out,
      (const float*)d_in[18], (const float*)d_in[19],
      (const float*)d_in[21], (const float*)d_in[22], (const float*)d_in[23],
      (float*)d_out);
}

// Round 15
// 316.988 us; speedup vs baseline: 1.2270x; 1.2270x over previous
//
#include <hip/hip_runtime.h>

#define B_ 512
#define T_ 256
#define F_ 8
#define H_ 128
#define BT_ (B_*T_)
#define MH_ 512
#define L2E 1.4426950408889634f

typedef __attribute__((ext_vector_type(4))) float f32x4;
typedef __attribute__((ext_vector_type(8))) __bf16 bf16x8;

// Static device scratch
// g_w2t: W2^T bf16, row n holds k-elems PRE-SWIZZLED: elem (k ^ ((n&7)<<3)).
__device__ unsigned short g_w2t[MH_*MH_];
// packed Whh/Wih bf16, [head][pc][k], PRE-SCALED: i,f,o rows by -log2e, g rows by +2log2e
__device__ unsigned short g_whh[3][512][128];
__device__ unsigned short g_wih[3][512][32];

__device__ __forceinline__ unsigned short f2bf(float f){
  unsigned int u = __float_as_uint(f);
  unsigned int r = (u + 0x7FFFu + ((u >> 16) & 1u)) >> 16;  // RNE
  return (unsigned short)r;
}

#if __has_builtin(__builtin_amdgcn_exp2f)
#define EXP2F __builtin_amdgcn_exp2f
#else
#define EXP2F exp2f
#endif
#define RCPF __builtin_amdgcn_rcpf

// DPP-based partial-sum step on the VALU pipe (verified +46us in r12).
template<int CTRL>
__device__ __forceinline__ float dpp_sum_step(float v){
  int t = __builtin_amdgcn_update_dpp(0, __float_as_int(v), CTRL, 0xF, 0xF, true);
  return v + __int_as_float(t);
}

// lgkm-only barrier: LDS h-exchange needs only lgkmcnt(0); skipping the
// vmcnt(0) drain keeps wave-0's D-store and the x-prefetch in flight
// across the barrier (T4). Isolated this round (r13 bundled it with a
// regressive ring-flush).
__device__ __forceinline__ void bar_lgkm(){
  asm volatile("s_waitcnt lgkmcnt(0)\n\ts_barrier" ::: "memory");
}

// load 8 consecutive f32 and convert to bf16x8 (prefetch phase, off-path)
__device__ __forceinline__ bf16x8 cvt_x8(const float* __restrict__ p){
  const f32x4 a = *(const f32x4*)p;
  const f32x4 b = *(const f32x4*)(p + 4);
  union { __bf16 e[8]; bf16x8 v; } u;
  #pragma unroll
  for (int i = 0; i < 4; ++i){ u.e[i] = (__bf16)a[i]; u.e[4+i] = (__bf16)b[i]; }
  return u.v;
}

struct LstmArgs {
  const float* x[3];
  const float* Wih[3];
  const float* Whh[3];
  const float* bias[3];
  const float* hw[3];
  const float* hb[3];
  float* out;
};

// Fused prep: W2^T pack (pre-swizzled) + Whh/Wih MFMA-order pack
// (pre-scaled by +-log2e). x is now converted inline in the LSTM kernel.
__global__ __launch_bounds__(256) void prep_all(LstmArgs A, const float* __restrict__ W2){
  const int NW2 = MH_*MH_;       // 262144
  const int NW  = 3*512*128;     // 196608
  const int NI  = 3*512*32;      // 49152
  const int TOT = NW2 + NW + NI;
  for (int i = blockIdx.x*256 + threadIdx.x; i < TOT; i += gridDim.x*256){
    if (i < NW2){
      int n = i >> 9;
      int k = i & 511;
      g_w2t[(n << 9) | (k ^ ((n & 7) << 3))] = f2bf(W2[(size_t)k * MH_ + n]);
    } else if (i < NW2 + NW){
      int j = i - NW2;
      int head = j >> 16;
      int r = j & 65535;
      int pc = r >> 7, k = r & 127;
      int w = pc >> 6, g = (pc >> 4) & 3, s = pc & 15;
      int row = g*128 + w*16 + s;
      float sc = (g == 2) ? (2.0f*L2E) : (-L2E);
      g_whh[head][pc][k] = f2bf(A.Whh[head][row*H_ + k] * sc);
    } else {
      int j = i - NW2 - NW;
      int head = j >> 14;
      int r = j & 16383;
      int pc = r >> 5, k = r & 31;
      int w = pc >> 6, g = (pc >> 4) & 3, s = pc & 15;
      int row = g*128 + w*16 + s;
      float sc = (g == 2) ? (2.0f*L2E) : (-L2E);
      g_wih[head][pc][k] = (k < 8) ? f2bf(A.Wih[head][row*F_ + k] * sc) : (unsigned short)0;
    }
  }
}

// MFMA LSTM — round-12 verified structure (best measured: 215us):
//  8-batch row-spread tiles, 192 blocks. batch b -> A/C row (b>>1)*4+(b&1)
//  => 2 cells/lane. exp2-form gates, weights pre-scaled by log2e.
//  Head-dot reduced one step LATE via DPP (VALU pipe, overlaps MFMA),
//  finalized by wave 0 after the barrier. h double-buffered in LDS.
//  Deltas vs r12: lgkm-only loop barrier; x read as f32 + inline cvt.
__global__ __launch_bounds__(512) void lstm_mfma_kernel(LstmArgs A){
  const int head   = blockIdx.x >> 6;          // 64 tiles per head, 192 blocks
  const int batch0 = (blockIdx.x & 63) * 8;
  const int tid = threadIdx.x;
  const int w   = tid >> 6;
  const int l   = tid & 63;
  const int c16 = l & 15;
  const int kb  = (l >> 4) * 8;

  const float* __restrict__ bs  = A.bias[head];
  const float* __restrict__ hwp = A.hw[head];
  const float hbv = A.hb[head][0];
  float* __restrict__ D = A.out + (size_t)head * BT_;

  // register-resident B-fragments
  bf16x8 bh[4][4];
  bf16x8 bx[4];
  #pragma unroll
  for (int g = 0; g < 4; ++g){
    const int pc = w*64 + g*16 + c16;
    #pragma unroll
    for (int kk = 0; kk < 4; ++kk)
      bh[g][kk] = *(const bf16x8*)&g_whh[head][pc][kk*32 + kb];
    bx[g] = *(const bf16x8*)&g_wih[head][pc][kb];
  }

  const int u = w*16 + c16;
  const float bi_ = bs[u]        * (-L2E);
  const float bf_ = bs[H_+u]     * (-L2E);
  const float bg_ = bs[2*H_+u]   * (2.0f*L2E);
  const float bo_ = bs[3*H_+u]   * (-L2E);
  const float hw_u = hwp[u];

  __shared__ __align__(16) unsigned short h_bf[2][16][132];
  __shared__ float part[2][8][8];

  for (int i = tid; i < 2*16*132; i += 512) ((unsigned short*)h_bf)[i] = 0;

  float cst[2] = {0.f, 0.f};
  float pp[2]  = {0.f, 0.f};

  // x A-row mapping: lane c16 supplies A-row c16; valid rows {0,1,4,5,8,9,12,13}
  const int bt = ((c16 >> 2) << 1) | (c16 & 1);          // batch-in-tile for row c16
  const bool xvalid = (l < 16) && !(l & 2);
  const float* __restrict__ xrowf =
      A.x[head] + (size_t)(batch0 + bt) * (T_*F_);

  bf16x8 ax_cur = {};
  if (xvalid) ax_cur = cvt_x8(xrowf);

  __syncthreads();

  int cur = 0;
  for (int ts = 0; ts < T_; ++ts){
    // A-frags for current h
    bf16x8 ah[4];
    #pragma unroll
    for (int kk = 0; kk < 4; ++kk)
      ah[kk] = *(const bf16x8*)&h_bf[cur][c16][kk*32 + kb];

    // prefetch+convert next step's x (off the critical path)
    bf16x8 ax_nxt = {};
    {
      const int tn = (ts + 1 < T_) ? ts + 1 : ts;
      if (xvalid) ax_nxt = cvt_x8(xrowf + tn*F_);
    }

    // h-MFMAs first (zero init), x-MFMA last
    f32x4 acc[4];
    const f32x4 z4 = {0.f, 0.f, 0.f, 0.f};
    #pragma unroll
    for (int g = 0; g < 4; ++g)
      acc[g] = __builtin_amdgcn_mfma_f32_16x16x32_bf16(ah[0], bh[g][0], z4, 0, 0, 0);
    #pragma unroll
    for (int kk = 1; kk < 4; ++kk){
      #pragma unroll
      for (int g = 0; g < 4; ++g)
        acc[g] = __builtin_amdgcn_mfma_f32_16x16x32_bf16(ah[kk], bh[g][kk], acc[g], 0, 0, 0);
    }
    #pragma unroll
    for (int g = 0; g < 4; ++g)
      acc[g] = __builtin_amdgcn_mfma_f32_16x16x32_bf16(ax_cur, bx[g], acc[g], 0, 0, 0);

    // previous step's head-dot reduction (DPP on VALU; overlaps MFMA)
    if (ts > 0){
      #pragma unroll
      for (int r = 0; r < 2; ++r){
        float v = pp[r];
        v = dpp_sum_step<0xB1>(v);    // ~xor1
        v = dpp_sum_step<0x4E>(v);    // ~xor2
        v = dpp_sum_step<0x141>(v);   // half-mirror (complementary quads)
        v = dpp_sum_step<0x140>(v);   // mirror (complementary octets)
        if (c16 == 0) part[(ts-1) & 1][(l >> 4)*2 + r][w] = v;
      }
    }

    // cell update: 2 cells/lane (regs r=0,1), exp2-form gates
    #pragma unroll
    for (int r = 0; r < 2; ++r){
      const float Zi = acc[0][r] + bi_;
      const float Zf = acc[1][r] + bf_;
      const float Zg = acc[2][r] + bg_;
      const float Zo = acc[3][r] + bo_;
      const float si = RCPF(1.f + EXP2F(Zi));
      const float sf = RCPF(1.f + EXP2F(Zf));
      const float tg = 1.f - 2.f * RCPF(EXP2F(Zg) + 1.f);
      const float so = RCPF(1.f + EXP2F(Zo));
      cst[r] = sf * cst[r] + si * tg;
      const float tc = 1.f - 2.f * RCPF(EXP2F(cst[r] * (2.0f*L2E)) + 1.f);
      const float hnr = so * tc;
      h_bf[cur ^ 1][(l >> 4)*4 + r][u] = f2bf(hnr);
      pp[r] = hnr * hw_u;                       // consumed next iteration
    }

    bar_lgkm();                                 // new h + part visible (lgkm only)

    // finalize D for step ts-1 (wave 0 only; overlaps other waves' next step)
    if (ts > 0 && tid < 64){
      const int b  = tid >> 3;
      const int wv = tid & 7;
      float v = part[(ts-1) & 1][b][wv];
      v = dpp_sum_step<0xB1>(v);
      v = dpp_sum_step<0x4E>(v);
      v = dpp_sum_step<0x141>(v);
      if (wv == 0) D[(size_t)(batch0 + b) * T_ + (ts-1)] = v + hbv;
    }

    ax_cur = ax_nxt;
    cur ^= 1;
  }

  // epilogue: step T-1's head-dot
  #pragma unroll
  for (int r = 0; r < 2; ++r){
    float v = pp[r];
    v = dpp_sum_step<0xB1>(v);
    v = dpp_sum_step<0x4E>(v);
    v = dpp_sum_step<0x141>(v);
    v = dpp_sum_step<0x140>(v);
    if (c16 == 0) part[(T_-1) & 1][(l >> 4)*2 + r][w] = v;
  }
  __syncthreads();
  if (tid < 64){
    const int b  = tid >> 3;
    const int wv = tid & 7;
    float v = part[(T_-1) & 1][b][wv];
    v = dpp_sum_step<0xB1>(v);
    v = dpp_sum_step<0x4E>(v);
    v = dpp_sum_step<0x141>(v);
    if (wv == 0) D[(size_t)(batch0 + b) * T_ + (T_-1)] = v + hbv;
  }
}

// Fused MLP v3 (verified ~50us, LDS-read-bound floor ~41us): 256 threads,
// 128 rows/block, grid 1024, launch_bounds(256,2). afr computed once.
// Full N in 16 passes of 32 cols; W2 slice double-buffered in LDS.
// Unchanged from round 12.
__global__ __launch_bounds__(256, 2) void mlp_kernel(
    const float* __restrict__ Dbase,
    const float* __restrict__ W1, const float* __restrict__ b1,
    const float* __restrict__ b2, const float* __restrict__ W3,
    const float* __restrict__ b3, float* __restrict__ out)
{
  __shared__ __align__(16) unsigned short buf[2][32*512];   // 2 x 32KB

  const int tid = threadIdx.x;
  const int l   = tid & 63;
  const int c16 = l & 15;
  const int kb  = (l >> 4) * 8;
  const int w   = tid >> 6;                 // 0..3
  const int m0  = blockIdx.x * 128 + w * 32;

  // A fragments for 2 M-tiles (computed once; live for whole kernel)
  bf16x8 afr[2][16];
  {
    float d[2][3];
    #pragma unroll
    for (int mt = 0; mt < 2; ++mt){
      const int gr = m0 + mt*16 + c16;
      d[mt][0] = Dbase[gr];
      d[mt][1] = Dbase[BT_ + gr];
      d[mt][2] = Dbase[2*BT_ + gr];
    }
    #pragma unroll
    for (int ks = 0; ks < 16; ++ks){
      const int kg = ks*32 + kb;
      const f32x4 wa0 = *(const f32x4*)(W1 + kg);          const f32x4 wa1 = *(const f32x4*)(W1 + kg + 4);
      const f32x4 wb0 = *(const f32x4*)(W1 + MH_ + kg);    const f32x4 wb1 = *(const f32x4*)(W1 + MH_ + kg + 4);
      const f32x4 wc0 = *(const f32x4*)(W1 + 2*MH_ + kg);  const f32x4 wc1 = *(const f32x4*)(W1 + 2*MH_ + kg + 4);
      const f32x4 bv0 = *(const f32x4*)(b1 + kg);          const f32x4 bv1 = *(const f32x4*)(b1 + kg + 4);
      #pragma unroll
      for (int mt = 0; mt < 2; ++mt){
        union { unsigned short us[8]; bf16x8 v; } au;
        #pragma unroll
        for (int i = 0; i < 4; ++i){
          float v0 = fmaf(d[mt][2], wc0[i], fmaf(d[mt][1], wb0[i], fmaf(d[mt][0], wa0[i], bv0[i])));
          float v1 = fmaf(d[mt][2], wc1[i], fmaf(d[mt][1], wb1[i], fmaf(d[mt][0], wa1[i], bv1[i])));
          au.us[i]     = f2bf(fmaxf(v0, 0.f));
          au.us[4 + i] = f2bf(fmaxf(v1, 0.f));
        }
        afr[mt][ks] = au.v;
      }
    }
  }

  // prologue: stage regs for pass 0 (pass = 32 cols = 2048 uint4; 8/thread)
  const uint4* __restrict__ gsrc = (const uint4*)g_w2t;
  uint4 rg0, rg1, rg2, rg3, rg4, rg5, rg6, rg7;
  {
    const uint4* s = gsrc + tid;
    rg0 = s[0*256]; rg1 = s[1*256]; rg2 = s[2*256]; rg3 = s[3*256];
    rg4 = s[4*256]; rg5 = s[5*256]; rg6 = s[6*256]; rg7 = s[7*256];
  }

  float rs[2][4] = {{0.f,0.f,0.f,0.f},{0.f,0.f,0.f,0.f}};

  #pragma unroll 1
  for (int p = 0; p < 16; ++p){
    {
      uint4* bw = (uint4*)buf[p & 1] + tid;
      bw[0*256] = rg0; bw[1*256] = rg1; bw[2*256] = rg2; bw[3*256] = rg3;
      bw[4*256] = rg4; bw[5*256] = rg5; bw[6*256] = rg6; bw[7*256] = rg7;
    }
    __syncthreads();               // write visible; dbuf makes this the ONLY barrier
    if (p < 15){
      const uint4* s = gsrc + (p + 1) * 2048 + tid;
      rg0 = s[0*256]; rg1 = s[1*256]; rg2 = s[2*256]; rg3 = s[3*256];
      rg4 = s[4*256]; rg5 = s[5*256]; rg6 = s[6*256]; rg7 = s[7*256];
    }
    float b2v[2], w3v[2];
    #pragma unroll
    for (int nt = 0; nt < 2; ++nt){
      const int n = p*32 + nt*16 + c16;
      b2v[nt] = b2[n];
      w3v[nt] = W3[n];
    }

    const unsigned short* __restrict__ bb = buf[p & 1];
    f32x4 acc[2][2];
    #pragma unroll
    for (int nt = 0; nt < 2; ++nt){
      f32x4 z = {0.f,0.f,0.f,0.f};
      acc[0][nt] = z; acc[1][nt] = z;
    }
    #pragma unroll
    for (int ks = 0; ks < 16; ++ks){
      #pragma unroll
      for (int nt = 0; nt < 2; ++nt){
        const int nl = nt*16 + c16;                    // local col 0..31
        const bf16x8 bfr =
          *(const bf16x8*)&bb[(nl << 9) | ((ks*32 + kb) ^ ((nl & 7) << 3))];
        acc[0][nt] = __builtin_amdgcn_mfma_f32_16x16x32_bf16(afr[0][ks], bfr, acc[0][nt], 0, 0, 0);
        acc[1][nt] = __builtin_amdgcn_mfma_f32_16x16x32_bf16(afr[1][ks], bfr, acc[1][nt], 0, 0, 0);
      }
    }
    #pragma unroll
    for (int nt = 0; nt < 2; ++nt){
      #pragma unroll
      for (int mt = 0; mt < 2; ++mt)
        #pragma unroll
        for (int r = 0; r < 4; ++r)
          rs[mt][r] += fmaxf(acc[mt][nt][r] + b2v[nt], 0.f) * w3v[nt];
    }
  }

  // reduce across the 16 lanes (c16 bits) sharing the same C-rows
  #pragma unroll
  for (int mt = 0; mt < 2; ++mt){
    #pragma unroll
    for (int r = 0; r < 4; ++r){
      rs[mt][r] += __shfl_xor(rs[mt][r], 1);
      rs[mt][r] += __shfl_xor(rs[mt][r], 2);
      rs[mt][r] += __shfl_xor(rs[mt][r], 4);
      rs[mt][r] += __shfl_xor(rs[mt][r], 8);
    }
  }
  if (c16 == 0){
    const float bv = b3[0];
    #pragma unroll
    for (int mt = 0; mt < 2; ++mt){
      const int row = m0 + mt*16 + (l >> 4) * 4;
      #pragma unroll
      for (int r = 0; r < 4; ++r)
        out[3*BT_ + row + r] = rs[mt][r] + bv;
    }
  }
}

extern "C" void kernel_launch(void* const* d_in, const int* in_sizes, int n_in,
                              void* d_out, int out_size, void* d_ws, size_t ws_size,
                              hipStream_t stream){
  LstmArgs A;
  for (int i = 0; i < 3; ++i){
    A.x[i]    = (const float*)d_in[i];
    A.Wih[i]  = (const float*)d_in[3 + i*5 + 0];
    A.Whh[i]  = (const float*)d_in[3 + i*5 + 1];
    A.bias[i] = (const float*)d_in[3 + i*5 + 2];
    A.hw[i]   = (const float*)d_in[3 + i*5 + 3];
    A.hb[i]   = (const float*)d_in[3 + i*5 + 4];
  }
  A.out = (float*)d_out;

  prep_all<<<dim3(1024), dim3(256), 0, stream>>>(A, (const float*)d_in[20]);
  lstm_mfma_kernel<<<dim3(192), dim3(512), 0, stream>>>(A);
  mlp_kernel<<<dim3(1024), dim3(256), 0, stream>>>((const float*)d_out,
      (const float*)d_in[18], (const float*)d_in[19],
      (const float*)d_in[21], (const float*)d_in[22], (const float*)d_in[23],
      (float*)d_out);
}

// Round 16
// 289.268 us; speedup vs baseline: 1.3446x; 1.0958x over previous
//
#include <hip/hip_runtime.h>

#define B_ 512
#define T_ 256
#define F_ 8
#define H_ 128
#define BT_ (B_*T_)
#define MH_ 512
#define L2E 1.4426950408889634f

typedef __attribute__((ext_vector_type(4))) float f32x4;
typedef __attribute__((ext_vector_type(8))) __bf16 bf16x8;

// Static device scratch
// g_w2t: W2^T bf16, row n holds k-elems PRE-SWIZZLED: elem (k ^ ((n&7)<<3)).
__device__ unsigned short g_w2t[MH_*MH_];
// packed Whh/Wih bf16, [head][pc][k], PRE-SCALED: i,f,o rows by -log2e, g rows by +2log2e
__device__ unsigned short g_whh[3][512][128];
__device__ unsigned short g_wih[3][512][32];
__device__ unsigned short g_xbf[3][B_*T_*F_];        // x in bf16, same (B,T,F) layout

__device__ __forceinline__ unsigned short f2bf(float f){
  unsigned int u = __float_as_uint(f);
  unsigned int r = (u + 0x7FFFu + ((u >> 16) & 1u)) >> 16;  // RNE
  return (unsigned short)r;
}

#if __has_builtin(__builtin_amdgcn_exp2f)
#define EXP2F __builtin_amdgcn_exp2f
#else
#define EXP2F exp2f
#endif
#define RCPF __builtin_amdgcn_rcpf

// DPP-based partial-sum step on the VALU pipe (verified +46us in r12).
template<int CTRL>
__device__ __forceinline__ float dpp_sum_step(float v){
  int t = __builtin_amdgcn_update_dpp(0, __float_as_int(v), CTRL, 0xF, 0xF, true);
  return v + __int_as_float(t);
}

struct LstmArgs {
  const float* x[3];
  const float* Wih[3];
  const float* Whh[3];
  const float* bias[3];
  const float* hw[3];
  const float* hb[3];
  float* out;
};

// One fused prep: W2^T pack (pre-swizzled) + Whh/Wih MFMA-order pack
// (pre-scaled by +-log2e) + x to bf16.  (r12 version, verified)
__global__ __launch_bounds__(256) void prep_all(LstmArgs A, const float* __restrict__ W2){
  const int NW2 = MH_*MH_;
  const int NW  = 3*512*128;
  const int NI  = 3*512*32;
  const int NX  = 3*B_*T_*F_;
  const int TOT = NW2 + NW + NI + NX;
  for (int i = blockIdx.x*256 + threadIdx.x; i < TOT; i += gridDim.x*256){
    if (i < NW2){
      int n = i >> 9;
      int k = i & 511;
      g_w2t[(n << 9) | (k ^ ((n & 7) << 3))] = f2bf(W2[(size_t)k * MH_ + n]);
    } else if (i < NW2 + NW){
      int j = i - NW2;
      int head = j >> 16;
      int r = j & 65535;
      int pc = r >> 7, k = r & 127;
      int w = pc >> 6, g = (pc >> 4) & 3, s = pc & 15;
      int row = g*128 + w*16 + s;
      float sc = (g == 2) ? (2.0f*L2E) : (-L2E);
      g_whh[head][pc][k] = f2bf(A.Whh[head][row*H_ + k] * sc);
    } else if (i < NW2 + NW + NI){
      int j = i - NW2 - NW;
      int head = j >> 14;
      int r = j & 16383;
      int pc = r >> 5, k = r & 31;
      int w = pc >> 6, g = (pc >> 4) & 3, s = pc & 15;
      int row = g*128 + w*16 + s;
      float sc = (g == 2) ? (2.0f*L2E) : (-L2E);
      g_wih[head][pc][k] = (k < 8) ? f2bf(A.Wih[head][row*F_ + k] * sc) : (unsigned short)0;
    } else {
      int j = i - NW2 - NW - NI;
      int head = j >> 20;
      int r = j & 1048575;
      g_xbf[head][r] = f2bf(A.x[head][r]);
    }
  }
}

// MFMA LSTM — r12 verified structure (215us base) with two local deltas:
//  (1) split MFMA accumulators: kk{0,1}->acc, kk{2,3}+x->acc2 (chains 5->2/3
//      deep, 8 independent streams), merged in the gate bias-adds.
//  (2) common-denominator gate algebra: 7 trans/cell (5 exp2 + 2 rcp) vs 10,
//      exact within f32 rounding; upper clamps keep products finite.
__global__ __launch_bounds__(512) void lstm_mfma_kernel(LstmArgs A){
  const int head   = blockIdx.x >> 6;          // 64 tiles per head, 192 blocks
  const int batch0 = (blockIdx.x & 63) * 8;
  const int tid = threadIdx.x;
  const int w   = tid >> 6;
  const int l   = tid & 63;
  const int c16 = l & 15;
  const int kb  = (l >> 4) * 8;

  const float* __restrict__ bs  = A.bias[head];
  const float* __restrict__ hwp = A.hw[head];
  const float hbv = A.hb[head][0];
  float* __restrict__ D = A.out + (size_t)head * BT_;

  // register-resident B-fragments
  bf16x8 bh[4][4];
  bf16x8 bx[4];
  #pragma unroll
  for (int g = 0; g < 4; ++g){
    const int pc = w*64 + g*16 + c16;
    #pragma unroll
    for (int kk = 0; kk < 4; ++kk)
      bh[g][kk] = *(const bf16x8*)&g_whh[head][pc][kk*32 + kb];
    bx[g] = *(const bf16x8*)&g_wih[head][pc][kb];
  }

  const int u = w*16 + c16;
  const float bi_ = bs[u]        * (-L2E);
  const float bf_ = bs[H_+u]     * (-L2E);
  const float bg_ = bs[2*H_+u]   * (2.0f*L2E);
  const float bo_ = bs[3*H_+u]   * (-L2E);
  const float hw_u = hwp[u];

  __shared__ __align__(16) unsigned short h_bf[2][16][132];
  __shared__ float part[2][8][8];

  for (int i = tid; i < 2*16*132; i += 512) ((unsigned short*)h_bf)[i] = 0;

  float cst[2] = {0.f, 0.f};
  float pp[2]  = {0.f, 0.f};

  // x A-row mapping: lane c16 supplies A-row c16; valid rows {0,1,4,5,8,9,12,13}
  const int bt = ((c16 >> 2) << 1) | (c16 & 1);          // batch-in-tile for row c16
  const bool xvalid = (l < 16) && !(l & 2);
  const unsigned short* __restrict__ xrow =
      &g_xbf[head][(size_t)(batch0 + bt) * (T_*F_)];

  bf16x8 ax_cur = {};
  if (xvalid) ax_cur = *(const bf16x8*)(xrow);

  __syncthreads();

  int cur = 0;
  for (int ts = 0; ts < T_; ++ts){
    // A-frags for current h
    bf16x8 ah[4];
    #pragma unroll
    for (int kk = 0; kk < 4; ++kk)
      ah[kk] = *(const bf16x8*)&h_bf[cur][c16][kk*32 + kb];

    // prefetch next step's x (off the critical path)
    bf16x8 ax_nxt = {};
    {
      const int tn = (ts + 1 < T_) ? ts + 1 : ts;
      if (xvalid) ax_nxt = *(const bf16x8*)(xrow + tn*F_);
    }

    // split-accumulator MFMAs: acc = kk{0,1}, acc2 = kk{2,3}+x
    f32x4 acc[4], acc2[4];
    const f32x4 z4 = {0.f, 0.f, 0.f, 0.f};
    #pragma unroll
    for (int g = 0; g < 4; ++g){
      acc[g]  = __builtin_amdgcn_mfma_f32_16x16x32_bf16(ah[0], bh[g][0], z4, 0, 0, 0);
      acc2[g] = __builtin_amdgcn_mfma_f32_16x16x32_bf16(ah[2], bh[g][2], z4, 0, 0, 0);
    }
    #pragma unroll
    for (int g = 0; g < 4; ++g){
      acc[g]  = __builtin_amdgcn_mfma_f32_16x16x32_bf16(ah[1], bh[g][1], acc[g],  0, 0, 0);
      acc2[g] = __builtin_amdgcn_mfma_f32_16x16x32_bf16(ah[3], bh[g][3], acc2[g], 0, 0, 0);
    }
    #pragma unroll
    for (int g = 0; g < 4; ++g)
      acc2[g] = __builtin_amdgcn_mfma_f32_16x16x32_bf16(ax_cur, bx[g], acc2[g], 0, 0, 0);

    // previous step's head-dot reduction (DPP on VALU; overlaps MFMA)
    if (ts > 0){
      #pragma unroll
      for (int r = 0; r < 2; ++r){
        float v = pp[r];
        v = dpp_sum_step<0xB1>(v);    // ~xor1
        v = dpp_sum_step<0x4E>(v);    // ~xor2
        v = dpp_sum_step<0x141>(v);   // half-mirror (complementary quads)
        v = dpp_sum_step<0x140>(v);   // mirror (complementary octets)
        if (c16 == 0) part[(ts-1) & 1][(l >> 4)*2 + r][w] = v;
      }
    }

    // cell update: 2 cells/lane, common-denominator form (7 trans/cell).
    //  sf*c + si*tg = (c*q + (pg-2)*pf) / (pi*pg*pf),  q = pi*pg
    //  so*tanh(c')  = (Ec-1) / (po*(1+Ec))
    // Upper clamps: Zi,Zf,Zo<=30, Zg<=60, 2c*L2E<=60 -> max product ~1.4e36.
    // Negative side saturates safely (exp2 underflow -> 0).
    #pragma unroll
    for (int r = 0; r < 2; ++r){
      const float Zi = fminf(acc[0][r] + acc2[0][r] + bi_, 30.f);
      const float Zf = fminf(acc[1][r] + acc2[1][r] + bf_, 30.f);
      const float Zg = fminf(acc[2][r] + acc2[2][r] + bg_, 60.f);
      const float Zo = fminf(acc[3][r] + acc2[3][r] + bo_, 30.f);
      const float Ei = EXP2F(Zi);
      const float Ef = EXP2F(Zf);
      const float Eg = EXP2F(Zg);
      const float Eo = EXP2F(Zo);
      const float pi_ = 1.f + Ei, pf_ = 1.f + Ef, pg_ = 1.f + Eg, po_ = 1.f + Eo;
      const float q  = pi_ * pg_;
      const float R  = RCPF(q * pf_);
      cst[r] = fmaf(cst[r], q, (pg_ - 2.f) * pf_) * R;
      const float a  = fminf(cst[r] * (2.0f*L2E), 60.f);
      const float Ec = EXP2F(a);
      const float S  = RCPF(po_ * (1.f + Ec));
      const float hnr = (Ec - 1.f) * S;
      h_bf[cur ^ 1][(l >> 4)*4 + r][u] = f2bf(hnr);
      pp[r] = hnr * hw_u;                       // consumed next iteration
    }

    __syncthreads();                            // new h + part visible

    // finalize D for step ts-1 (wave 0 only; overlaps other waves' next step)
    if (ts > 0 && tid < 64){
      const int b  = tid >> 3;
      const int wv = tid & 7;
      float v = part[(ts-1) & 1][b][wv];
      v = dpp_sum_step<0xB1>(v);
      v = dpp_sum_step<0x4E>(v);
      v = dpp_sum_step<0x141>(v);
      if (wv == 0) D[(size_t)(batch0 + b) * T_ + (ts-1)] = v + hbv;
    }

    ax_cur = ax_nxt;
    cur ^= 1;
  }

  // epilogue: step T-1's head-dot
  #pragma unroll
  for (int r = 0; r < 2; ++r){
    float v = pp[r];
    v = dpp_sum_step<0xB1>(v);
    v = dpp_sum_step<0x4E>(v);
    v = dpp_sum_step<0x141>(v);
    v = dpp_sum_step<0x140>(v);
    if (c16 == 0) part[(T_-1) & 1][(l >> 4)*2 + r][w] = v;
  }
  __syncthreads();
  if (tid < 64){
    const int b  = tid >> 3;
    const int wv = tid & 7;
    float v = part[(T_-1) & 1][b][wv];
    v = dpp_sum_step<0xB1>(v);
    v = dpp_sum_step<0x4E>(v);
    v = dpp_sum_step<0x141>(v);
    if (wv == 0) D[(size_t)(batch0 + b) * T_ + (T_-1)] = v + hbv;
  }
}

// Fused MLP v3 (verified ~50us, LDS-read-bound floor ~41us): 256 threads,
// 128 rows/block, grid 1024, launch_bounds(256,2). afr computed once.
// Full N in 16 passes of 32 cols; W2 slice double-buffered in LDS.
// Unchanged from round 12.
__global__ __launch_bounds__(256, 2) void mlp_kernel(
    const float* __restrict__ Dbase,
    const float* __restrict__ W1, const float* __restrict__ b1,
    const float* __restrict__ b2, const float* __restrict__ W3,
    const float* __restrict__ b3, float* __restrict__ out)
{
  __shared__ __align__(16) unsigned short buf[2][32*512];   // 2 x 32KB

  const int tid = threadIdx.x;
  const int l   = tid & 63;
  const int c16 = l & 15;
  const int kb  = (l >> 4) * 8;
  const int w   = tid >> 6;                 // 0..3
  const int m0  = blockIdx.x * 128 + w * 32;

  // A fragments for 2 M-tiles (computed once; live for whole kernel)
  bf16x8 afr[2][16];
  {
    float d[2][3];
    #pragma unroll
    for (int mt = 0; mt < 2; ++mt){
      const int gr = m0 + mt*16 + c16;
      d[mt][0] = Dbase[gr];
      d[mt][1] = Dbase[BT_ + gr];
      d[mt][2] = Dbase[2*BT_ + gr];
    }
    #pragma unroll
    for (int ks = 0; ks < 16; ++ks){
      const int kg = ks*32 + kb;
      const f32x4 wa0 = *(const f32x4*)(W1 + kg);          const f32x4 wa1 = *(const f32x4*)(W1 + kg + 4);
      const f32x4 wb0 = *(const f32x4*)(W1 + MH_ + kg);    const f32x4 wb1 = *(const f32x4*)(W1 + MH_ + kg + 4);
      const f32x4 wc0 = *(const f32x4*)(W1 + 2*MH_ + kg);  const f32x4 wc1 = *(const f32x4*)(W1 + 2*MH_ + kg + 4);
      const f32x4 bv0 = *(const f32x4*)(b1 + kg);          const f32x4 bv1 = *(const f32x4*)(b1 + kg + 4);
      #pragma unroll
      for (int mt = 0; mt < 2; ++mt){
        union { unsigned short us[8]; bf16x8 v; } au;
        #pragma unroll
        for (int i = 0; i < 4; ++i){
          float v0 = fmaf(d[mt][2], wc0[i], fmaf(d[mt][1], wb0[i], fmaf(d[mt][0], wa0[i], bv0[i])));
          float v1 = fmaf(d[mt][2], wc1[i], fmaf(d[mt][1], wb1[i], fmaf(d[mt][0], wa1[i], bv1[i])));
          au.us[i]     = f2bf(fmaxf(v0, 0.f));
          au.us[4 + i] = f2bf(fmaxf(v1, 0.f));
        }
        afr[mt][ks] = au.v;
      }
    }
  }

  // prologue: stage regs for pass 0 (pass = 32 cols = 2048 uint4; 8/thread)
  const uint4* __restrict__ gsrc = (const uint4*)g_w2t;
  uint4 rg0, rg1, rg2, rg3, rg4, rg5, rg6, rg7;
  {
    const uint4* s = gsrc + tid;
    rg0 = s[0*256]; rg1 = s[1*256]; rg2 = s[2*256]; rg3 = s[3*256];
    rg4 = s[4*256]; rg5 = s[5*256]; rg6 = s[6*256]; rg7 = s[7*256];
  }

  float rs[2][4] = {{0.f,0.f,0.f,0.f},{0.f,0.f,0.f,0.f}};

  #pragma unroll 1
  for (int p = 0; p < 16; ++p){
    {
      uint4* bw = (uint4*)buf[p & 1] + tid;
      bw[0*256] = rg0; bw[1*256] = rg1; bw[2*256] = rg2; bw[3*256] = rg3;
      bw[4*256] = rg4; bw[5*256] = rg5; bw[6*256] = rg6; bw[7*256] = rg7;
    }
    __syncthreads();               // write visible; dbuf makes this the ONLY barrier
    if (p < 15){
      const uint4* s = gsrc + (p + 1) * 2048 + tid;
      rg0 = s[0*256]; rg1 = s[1*256]; rg2 = s[2*256]; rg3 = s[3*256];
      rg4 = s[4*256]; rg5 = s[5*256]; rg6 = s[6*256]; rg7 = s[7*256];
    }
    float b2v[2], w3v[2];
    #pragma unroll
    for (int nt = 0; nt < 2; ++nt){
      const int n = p*32 + nt*16 + c16;
      b2v[nt] = b2[n];
      w3v[nt] = W3[n];
    }

    const unsigned short* __restrict__ bb = buf[p & 1];
    f32x4 acc[2][2];
    #pragma unroll
    for (int nt = 0; nt < 2; ++nt){
      f32x4 z = {0.f,0.f,0.f,0.f};
      acc[0][nt] = z; acc[1][nt] = z;
    }
    #pragma unroll
    for (int ks = 0; ks < 16; ++ks){
      #pragma unroll
      for (int nt = 0; nt < 2; ++nt){
        const int nl = nt*16 + c16;                    // local col 0..31
        const bf16x8 bfr =
          *(const bf16x8*)&bb[(nl << 9) | ((ks*32 + kb) ^ ((nl & 7) << 3))];
        acc[0][nt] = __builtin_amdgcn_mfma_f32_16x16x32_bf16(afr[0][ks], bfr, acc[0][nt], 0, 0, 0);
        acc[1][nt] = __builtin_amdgcn_mfma_f32_16x16x32_bf16(afr[1][ks], bfr, acc[1][nt], 0, 0, 0);
      }
    }
    #pragma unroll
    for (int nt = 0; nt < 2; ++nt){
      #pragma unroll
      for (int mt = 0; mt < 2; ++mt)
        #pragma unroll
        for (int r = 0; r < 4; ++r)
          rs[mt][r] += fmaxf(acc[mt][nt][r] + b2v[nt], 0.f) * w3v[nt];
    }
  }

  // reduce across the 16 lanes (c16 bits) sharing the same C-rows
  #pragma unroll
  for (int mt = 0; mt < 2; ++mt){
    #pragma unroll
    for (int r = 0; r < 4; ++r){
      rs[mt][r] += __shfl_xor(rs[mt][r], 1);
      rs[mt][r] += __shfl_xor(rs[mt][r], 2);
      rs[mt][r] += __shfl_xor(rs[mt][r], 4);
      rs[mt][r] += __shfl_xor(rs[mt][r], 8);
    }
  }
  if (c16 == 0){
    const float bv = b3[0];
    #pragma unroll
    for (int mt = 0; mt < 2; ++mt){
      const int row = m0 + mt*16 + (l >> 4) * 4;
      #pragma unroll
      for (int r = 0; r < 4; ++r)
        out[3*BT_ + row + r] = rs[mt][r] + bv;
    }
  }
}

extern "C" void kernel_launch(void* const* d_in, const int* in_sizes, int n_in,
                              void* d_out, int out_size, void* d_ws, size_t ws_size,
                              hipStream_t stream){
  LstmArgs A;
  for (int i = 0; i < 3; ++i){
    A.x[i]    = (const float*)d_in[i];
    A.Wih[i]  = (const float*)d_in[3 + i*5 + 0];
    A.Whh[i]  = (const float*)d_in[3 + i*5 + 1];
    A.bias[i] = (const float*)d_in[3 + i*5 + 2];
    A.hw[i]   = (const float*)d_in[3 + i*5 + 3];
    A.hb[i]   = (const float*)d_in[3 + i*5 + 4];
  }
  A.out = (float*)d_out;

  prep_all<<<dim3(2048), dim3(256), 0, stream>>>(A, (const float*)d_in[20]);
  lstm_mfma_kernel<<<dim3(192), dim3(512), 0, stream>>>(A);
  mlp_kernel<<<dim3(1024), dim3(256), 0, stream>>>((const float*)d_out,
      (const float*)d_in[18], (const float*)d_in[19],
      (const float*)d_in[21], (const float*)d_in[22], (const float*)d_in[23],
      (float*)d_out);
}

// Round 17
// 278.527 us; speedup vs baseline: 1.3964x; 1.0386x over previous
//
#include <hip/hip_runtime.h>

#define B_ 512
#define T_ 256
#define F_ 8
#define H_ 128
#define BT_ (B_*T_)
#define MH_ 512
#define L2E 1.4426950408889634f

typedef __attribute__((ext_vector_type(4))) float f32x4;
typedef __attribute__((ext_vector_type(8))) __bf16 bf16x8;

// Static device scratch
// g_w2t: W2^T bf16, row n holds k-elems PRE-SWIZZLED: elem (k ^ ((n&7)<<3)).
__device__ unsigned short g_w2t[MH_*MH_];
// packed Whh/Wih bf16, [head][pc][k], PRE-SCALED: i,f,o rows by -log2e, g rows by +2log2e
__device__ unsigned short g_whh[3][512][128];
__device__ unsigned short g_wih[3][512][32];
__device__ unsigned short g_xbf[3][B_*T_*F_];        // x in bf16, same (B,T,F) layout

__device__ __forceinline__ unsigned short f2bf(float f){
  unsigned int u = __float_as_uint(f);
  unsigned int r = (u + 0x7FFFu + ((u >> 16) & 1u)) >> 16;  // RNE
  return (unsigned short)r;
}

#if __has_builtin(__builtin_amdgcn_exp2f)
#define EXP2F __builtin_amdgcn_exp2f
#else
#define EXP2F exp2f
#endif
#define RCPF __builtin_amdgcn_rcpf

// DPP-based partial-sum step on the VALU pipe (verified +46us in r12).
template<int CTRL>
__device__ __forceinline__ float dpp_sum_step(float v){
  int t = __builtin_amdgcn_update_dpp(0, __float_as_int(v), CTRL, 0xF, 0xF, true);
  return v + __int_as_float(t);
}

// lgkm-only barrier (THE isolated delta this round): __syncthreads emits
// s_waitcnt vmcnt(0) lgkmcnt(0), draining wave-0's per-step D-store and the
// x-prefetch at every barrier. LDS h/part exchange needs only lgkmcnt(0);
// the vmcnt ops here are store-only or RAR, so skipping the drain is safe.
__device__ __forceinline__ void bar_lgkm(){
  asm volatile("s_waitcnt lgkmcnt(0)\n\ts_barrier" ::: "memory");
}

struct LstmArgs {
  const float* x[3];
  const float* Wih[3];
  const float* Whh[3];
  const float* bias[3];
  const float* hw[3];
  const float* hb[3];
  float* out;
};

// One fused prep: W2^T pack (pre-swizzled) + Whh/Wih MFMA-order pack
// (pre-scaled by +-log2e) + x to bf16.  (r12 version, verified)
__global__ __launch_bounds__(256) void prep_all(LstmArgs A, const float* __restrict__ W2){
  const int NW2 = MH_*MH_;
  const int NW  = 3*512*128;
  const int NI  = 3*512*32;
  const int NX  = 3*B_*T_*F_;
  const int TOT = NW2 + NW + NI + NX;
  for (int i = blockIdx.x*256 + threadIdx.x; i < TOT; i += gridDim.x*256){
    if (i < NW2){
      int n = i >> 9;
      int k = i & 511;
      g_w2t[(n << 9) | (k ^ ((n & 7) << 3))] = f2bf(W2[(size_t)k * MH_ + n]);
    } else if (i < NW2 + NW){
      int j = i - NW2;
      int head = j >> 16;
      int r = j & 65535;
      int pc = r >> 7, k = r & 127;
      int w = pc >> 6, g = (pc >> 4) & 3, s = pc & 15;
      int row = g*128 + w*16 + s;
      float sc = (g == 2) ? (2.0f*L2E) : (-L2E);
      g_whh[head][pc][k] = f2bf(A.Whh[head][row*H_ + k] * sc);
    } else if (i < NW2 + NW + NI){
      int j = i - NW2 - NW;
      int head = j >> 14;
      int r = j & 16383;
      int pc = r >> 5, k = r & 31;
      int w = pc >> 6, g = (pc >> 4) & 3, s = pc & 15;
      int row = g*128 + w*16 + s;
      float sc = (g == 2) ? (2.0f*L2E) : (-L2E);
      g_wih[head][pc][k] = (k < 8) ? f2bf(A.Wih[head][row*F_ + k] * sc) : (unsigned short)0;
    } else {
      int j = i - NW2 - NW - NI;
      int head = j >> 20;
      int r = j & 1048575;
      g_xbf[head][r] = f2bf(A.x[head][r]);
    }
  }
}

// MFMA LSTM — r12 verified structure (best measured: 215us), byte-exact,
// with ONE delta: lgkm-only loop barrier (no vmcnt drain).
//  8-batch row-spread tiles, 192 blocks. batch b -> A/C row (b>>1)*4+(b&1)
//  => 2 cells/lane. exp2-form gates, weights pre-scaled by log2e.
//  Head-dot reduced one step LATE via DPP (VALU pipe, overlaps MFMA),
//  finalized by wave 0 after the barrier. h double-buffered in LDS.
__global__ __launch_bounds__(512) void lstm_mfma_kernel(LstmArgs A){
  const int head   = blockIdx.x >> 6;          // 64 tiles per head, 192 blocks
  const int batch0 = (blockIdx.x & 63) * 8;
  const int tid = threadIdx.x;
  const int w   = tid >> 6;
  const int l   = tid & 63;
  const int c16 = l & 15;
  const int kb  = (l >> 4) * 8;

  const float* __restrict__ bs  = A.bias[head];
  const float* __restrict__ hwp = A.hw[head];
  const float hbv = A.hb[head][0];
  float* __restrict__ D = A.out + (size_t)head * BT_;

  // register-resident B-fragments
  bf16x8 bh[4][4];
  bf16x8 bx[4];
  #pragma unroll
  for (int g = 0; g < 4; ++g){
    const int pc = w*64 + g*16 + c16;
    #pragma unroll
    for (int kk = 0; kk < 4; ++kk)
      bh[g][kk] = *(const bf16x8*)&g_whh[head][pc][kk*32 + kb];
    bx[g] = *(const bf16x8*)&g_wih[head][pc][kb];
  }

  const int u = w*16 + c16;
  const float bi_ = bs[u]        * (-L2E);
  const float bf_ = bs[H_+u]     * (-L2E);
  const float bg_ = bs[2*H_+u]   * (2.0f*L2E);
  const float bo_ = bs[3*H_+u]   * (-L2E);
  const float hw_u = hwp[u];

  __shared__ __align__(16) unsigned short h_bf[2][16][132];
  __shared__ float part[2][8][8];

  for (int i = tid; i < 2*16*132; i += 512) ((unsigned short*)h_bf)[i] = 0;

  float cst[2] = {0.f, 0.f};
  float pp[2]  = {0.f, 0.f};

  // x A-row mapping: lane c16 supplies A-row c16; valid rows {0,1,4,5,8,9,12,13}
  const int bt = ((c16 >> 2) << 1) | (c16 & 1);          // batch-in-tile for row c16
  const bool xvalid = (l < 16) && !(l & 2);
  const unsigned short* __restrict__ xrow =
      &g_xbf[head][(size_t)(batch0 + bt) * (T_*F_)];

  bf16x8 ax_cur = {};
  if (xvalid) ax_cur = *(const bf16x8*)(xrow);

  __syncthreads();

  int cur = 0;
  for (int ts = 0; ts < T_; ++ts){
    // A-frags for current h
    bf16x8 ah[4];
    #pragma unroll
    for (int kk = 0; kk < 4; ++kk)
      ah[kk] = *(const bf16x8*)&h_bf[cur][c16][kk*32 + kb];

    // prefetch next step's x (off the critical path; stays in flight across barrier)
    bf16x8 ax_nxt = {};
    {
      const int tn = (ts + 1 < T_) ? ts + 1 : ts;
      if (xvalid) ax_nxt = *(const bf16x8*)(xrow + tn*F_);
    }

    // h-MFMAs first (zero init), x-MFMA last
    f32x4 acc[4];
    const f32x4 z4 = {0.f, 0.f, 0.f, 0.f};
    #pragma unroll
    for (int g = 0; g < 4; ++g)
      acc[g] = __builtin_amdgcn_mfma_f32_16x16x32_bf16(ah[0], bh[g][0], z4, 0, 0, 0);
    #pragma unroll
    for (int kk = 1; kk < 4; ++kk){
      #pragma unroll
      for (int g = 0; g < 4; ++g)
        acc[g] = __builtin_amdgcn_mfma_f32_16x16x32_bf16(ah[kk], bh[g][kk], acc[g], 0, 0, 0);
    }
    #pragma unroll
    for (int g = 0; g < 4; ++g)
      acc[g] = __builtin_amdgcn_mfma_f32_16x16x32_bf16(ax_cur, bx[g], acc[g], 0, 0, 0);

    // previous step's head-dot reduction (DPP on VALU; overlaps MFMA)
    if (ts > 0){
      #pragma unroll
      for (int r = 0; r < 2; ++r){
        float v = pp[r];
        v = dpp_sum_step<0xB1>(v);    // ~xor1
        v = dpp_sum_step<0x4E>(v);    // ~xor2
        v = dpp_sum_step<0x141>(v);   // half-mirror (complementary quads)
        v = dpp_sum_step<0x140>(v);   // mirror (complementary octets)
        if (c16 == 0) part[(ts-1) & 1][(l >> 4)*2 + r][w] = v;
      }
    }

    // cell update: 2 cells/lane (regs r=0,1), exp2-form gates
    #pragma unroll
    for (int r = 0; r < 2; ++r){
      const float Zi = acc[0][r] + bi_;
      const float Zf = acc[1][r] + bf_;
      const float Zg = acc[2][r] + bg_;
      const float Zo = acc[3][r] + bo_;
      const float si = RCPF(1.f + EXP2F(Zi));
      const float sf = RCPF(1.f + EXP2F(Zf));
      const float tg = 1.f - 2.f * RCPF(EXP2F(Zg) + 1.f);
      const float so = RCPF(1.f + EXP2F(Zo));
      cst[r] = sf * cst[r] + si * tg;
      const float tc = 1.f - 2.f * RCPF(EXP2F(cst[r] * (2.0f*L2E)) + 1.f);
      const float hnr = so * tc;
      h_bf[cur ^ 1][(l >> 4)*4 + r][u] = f2bf(hnr);
      pp[r] = hnr * hw_u;                       // consumed next iteration
    }

    bar_lgkm();                                 // new h + part visible (lgkm only)

    // finalize D for step ts-1 (wave 0 only; overlaps other waves' next step)
    if (ts > 0 && tid < 64){
      const int b  = tid >> 3;
      const int wv = tid & 7;
      float v = part[(ts-1) & 1][b][wv];
      v = dpp_sum_step<0xB1>(v);
      v = dpp_sum_step<0x4E>(v);
      v = dpp_sum_step<0x141>(v);
      if (wv == 0) D[(size_t)(batch0 + b) * T_ + (ts-1)] = v + hbv;
    }

    ax_cur = ax_nxt;
    cur ^= 1;
  }

  // epilogue: step T-1's head-dot
  #pragma unroll
  for (int r = 0; r < 2; ++r){
    float v = pp[r];
    v = dpp_sum_step<0xB1>(v);
    v = dpp_sum_step<0x4E>(v);
    v = dpp_sum_step<0x141>(v);
    v = dpp_sum_step<0x140>(v);
    if (c16 == 0) part[(T_-1) & 1][(l >> 4)*2 + r][w] = v;
  }
  __syncthreads();
  if (tid < 64){
    const int b  = tid >> 3;
    const int wv = tid & 7;
    float v = part[(T_-1) & 1][b][wv];
    v = dpp_sum_step<0xB1>(v);
    v = dpp_sum_step<0x4E>(v);
    v = dpp_sum_step<0x141>(v);
    if (wv == 0) D[(size_t)(batch0 + b) * T_ + (T_-1)] = v + hbv;
  }
}

// Fused MLP v4: 512 blocks x 512 threads (8 waves), 256 rows/block.
// Same inner code as v3 (afr[2][16] per wave = 128 VGPR), but each staged
// W2 pass now serves 8 waves instead of 4 -> total W2 L2 traffic halves
// (512 -> 256 MB) and barriers-per-row halve. __launch_bounds__(512,1):
// VGPR cap 256 (NOT (512,2): cap 128 would spill afr — r8/r9 lesson).
__global__ __launch_bounds__(512, 1) void mlp_kernel(
    const float* __restrict__ Dbase,
    const float* __restrict__ W1, const float* __restrict__ b1,
    const float* __restrict__ b2, const float* __restrict__ W3,
    const float* __restrict__ b3, float* __restrict__ out)
{
  __shared__ __align__(16) unsigned short buf[2][32*512];   // 2 x 32KB

  const int tid = threadIdx.x;
  const int l   = tid & 63;
  const int c16 = l & 15;
  const int kb  = (l >> 4) * 8;
  const int w   = tid >> 6;                 // 0..7
  const int m0  = blockIdx.x * 256 + w * 32;

  // A fragments for 2 M-tiles (computed once; live for whole kernel)
  bf16x8 afr[2][16];
  {
    float d[2][3];
    #pragma unroll
    for (int mt = 0; mt < 2; ++mt){
      const int gr = m0 + mt*16 + c16;
      d[mt][0] = Dbase[gr];
      d[mt][1] = Dbase[BT_ + gr];
      d[mt][2] = Dbase[2*BT_ + gr];
    }
    #pragma unroll
    for (int ks = 0; ks < 16; ++ks){
      const int kg = ks*32 + kb;
      const f32x4 wa0 = *(const f32x4*)(W1 + kg);          const f32x4 wa1 = *(const f32x4*)(W1 + kg + 4);
      const f32x4 wb0 = *(const f32x4*)(W1 + MH_ + kg);    const f32x4 wb1 = *(const f32x4*)(W1 + MH_ + kg + 4);
      const f32x4 wc0 = *(const f32x4*)(W1 + 2*MH_ + kg);  const f32x4 wc1 = *(const f32x4*)(W1 + 2*MH_ + kg + 4);
      const f32x4 bv0 = *(const f32x4*)(b1 + kg);          const f32x4 bv1 = *(const f32x4*)(b1 + kg + 4);
      #pragma unroll
      for (int mt = 0; mt < 2; ++mt){
        union { unsigned short us[8]; bf16x8 v; } au;
        #pragma unroll
        for (int i = 0; i < 4; ++i){
          float v0 = fmaf(d[mt][2], wc0[i], fmaf(d[mt][1], wb0[i], fmaf(d[mt][0], wa0[i], bv0[i])));
          float v1 = fmaf(d[mt][2], wc1[i], fmaf(d[mt][1], wb1[i], fmaf(d[mt][0], wa1[i], bv1[i])));
          au.us[i]     = f2bf(fmaxf(v0, 0.f));
          au.us[4 + i] = f2bf(fmaxf(v1, 0.f));
        }
        afr[mt][ks] = au.v;
      }
    }
  }

  // prologue: stage regs for pass 0 (pass = 32 cols = 2048 uint4; 4/thread)
  const uint4* __restrict__ gsrc = (const uint4*)g_w2t;
  uint4 rg0, rg1, rg2, rg3;
  {
    const uint4* s = gsrc + tid;
    rg0 = s[0*512]; rg1 = s[1*512]; rg2 = s[2*512]; rg3 = s[3*512];
  }

  float rs[2][4] = {{0.f,0.f,0.f,0.f},{0.f,0.f,0.f,0.f}};

  #pragma unroll 1
  for (int p = 0; p < 16; ++p){
    {
      uint4* bw = (uint4*)buf[p & 1] + tid;
      bw[0*512] = rg0; bw[1*512] = rg1; bw[2*512] = rg2; bw[3*512] = rg3;
    }
    __syncthreads();               // write visible; dbuf makes this the ONLY barrier
    if (p < 15){
      const uint4* s = gsrc + (p + 1) * 2048 + tid;
      rg0 = s[0*512]; rg1 = s[1*512]; rg2 = s[2*512]; rg3 = s[3*512];
    }
    float b2v[2], w3v[2];
    #pragma unroll
    for (int nt = 0; nt < 2; ++nt){
      const int n = p*32 + nt*16 + c16;
      b2v[nt] = b2[n];
      w3v[nt] = W3[n];
    }

    const unsigned short* __restrict__ bb = buf[p & 1];
    f32x4 acc[2][2];
    #pragma unroll
    for (int nt = 0; nt < 2; ++nt){
      f32x4 z = {0.f,0.f,0.f,0.f};
      acc[0][nt] = z; acc[1][nt] = z;
    }
    #pragma unroll
    for (int ks = 0; ks < 16; ++ks){
      #pragma unroll
      for (int nt = 0; nt < 2; ++nt){
        const int nl = nt*16 + c16;                    // local col 0..31
        const bf16x8 bfr =
          *(const bf16x8*)&bb[(nl << 9) | ((ks*32 + kb) ^ ((nl & 7) << 3))];
        acc[0][nt] = __builtin_amdgcn_mfma_f32_16x16x32_bf16(afr[0][ks], bfr, acc[0][nt], 0, 0, 0);
        acc[1][nt] = __builtin_amdgcn_mfma_f32_16x16x32_bf16(afr[1][ks], bfr, acc[1][nt], 0, 0, 0);
      }
    }
    #pragma unroll
    for (int nt = 0; nt < 2; ++nt){
      #pragma unroll
      for (int mt = 0; mt < 2; ++mt)
        #pragma unroll
        for (int r = 0; r < 4; ++r)
          rs[mt][r] += fmaxf(acc[mt][nt][r] + b2v[nt], 0.f) * w3v[nt];
    }
  }

  // reduce across the 16 lanes (c16 bits) sharing the same C-rows
  #pragma unroll
  for (int mt = 0; mt < 2; ++mt){
    #pragma unroll
    for (int r = 0; r < 4; ++r){
      rs[mt][r] += __shfl_xor(rs[mt][r], 1);
      rs[mt][r] += __shfl_xor(rs[mt][r], 2);
      rs[mt][r] += __shfl_xor(rs[mt][r], 4);
      rs[mt][r] += __shfl_xor(rs[mt][r], 8);
    }
  }
  if (c16 == 0){
    const float bv = b3[0];
    #pragma unroll
    for (int mt = 0; mt < 2; ++mt){
      const int row = m0 + mt*16 + (l >> 4) * 4;
      #pragma unroll
      for (int r = 0; r < 4; ++r)
        out[3*BT_ + row + r] = rs[mt][r] + bv;
    }
  }
}

extern "C" void kernel_launch(void* const* d_in, const int* in_sizes, int n_in,
                              void* d_out, int out_size, void* d_ws, size_t ws_size,
                              hipStream_t stream){
  LstmArgs A;
  for (int i = 0; i < 3; ++i){
    A.x[i]    = (const float*)d_in[i];
    A.Wih[i]  = (const float*)d_in[3 + i*5 + 0];
    A.Whh[i]  = (const float*)d_in[3 + i*5 + 1];
    A.bias[i] = (const float*)d_in[3 + i*5 + 2];
    A.hw[i]   = (const float*)d_in[3 + i*5 + 3];
    A.hb[i]   = (const float*)d_in[3 + i*5 + 4];
  }
  A.out = (float*)d_out;

  prep_all<<<dim3(2048), dim3(256), 0, stream>>>(A, (const float*)d_in[20]);
  lstm_mfma_kernel<<<dim3(192), dim3(512), 0, stream>>>(A);
  mlp_kernel<<<dim3(512), dim3(512), 0, stream>>>((const float*)d_out,
      (const float*)d_in[18], (const float*)d_in[19],
      (const float*)d_in[21], (const float*)d_in[22], (const float*)d_in[23],
      (float*)d_out);
}

// Round 18
// 275.046 us; speedup vs baseline: 1.4141x; 1.0127x over previous
//
#include <hip/hip_runtime.h>

#define B_ 512
#define T_ 256
#define F_ 8
#define H_ 128
#define BT_ (B_*T_)
#define MH_ 512
#define L2E 1.4426950408889634f

typedef __attribute__((ext_vector_type(4))) float f32x4;
typedef __attribute__((ext_vector_type(8))) __bf16 bf16x8;

// Static device scratch
// g_w2t: W2^T bf16, row n holds k-elems PRE-SWIZZLED: elem (k ^ ((n&7)<<3)).
__device__ unsigned short g_w2t[MH_*MH_];
// packed Whh/Wih bf16, [head][pc][k], PRE-SCALED: i,f,o rows by -log2e, g rows by +2log2e
__device__ unsigned short g_whh[3][512][128];
__device__ unsigned short g_wih[3][512][32];
__device__ unsigned short g_xbf[3][B_*T_*F_];        // x in bf16, same (B,T,F) layout

__device__ __forceinline__ unsigned short f2bf(float f){
  unsigned int u = __float_as_uint(f);
  unsigned int r = (u + 0x7FFFu + ((u >> 16) & 1u)) >> 16;  // RNE
  return (unsigned short)r;
}

#if __has_builtin(__builtin_amdgcn_exp2f)
#define EXP2F __builtin_amdgcn_exp2f
#else
#define EXP2F exp2f
#endif
#define RCPF __builtin_amdgcn_rcpf

// DPP-based partial-sum step on the VALU pipe (verified +46us in r12).
template<int CTRL>
__device__ __forceinline__ float dpp_sum_step(float v){
  int t = __builtin_amdgcn_update_dpp(0, __float_as_int(v), CTRL, 0xF, 0xF, true);
  return v + __int_as_float(t);
}

// lgkm-only barrier (measured exactly neutral vs __syncthreads in r17;
// kept because r17 is the verified-best base).
__device__ __forceinline__ void bar_lgkm(){
  asm volatile("s_waitcnt lgkmcnt(0)\n\ts_barrier" ::: "memory");
}

struct LstmArgs {
  const float* x[3];
  const float* Wih[3];
  const float* Whh[3];
  const float* bias[3];
  const float* hw[3];
  const float* hb[3];
  float* out;
};

// One fused prep: W2^T pack (pre-swizzled) + Whh/Wih MFMA-order pack
// (pre-scaled by +-log2e) + x to bf16.  (r12 version, verified)
__global__ __launch_bounds__(256) void prep_all(LstmArgs A, const float* __restrict__ W2){
  const int NW2 = MH_*MH_;
  const int NW  = 3*512*128;
  const int NI  = 3*512*32;
  const int NX  = 3*B_*T_*F_;
  const int TOT = NW2 + NW + NI + NX;
  for (int i = blockIdx.x*256 + threadIdx.x; i < TOT; i += gridDim.x*256){
    if (i < NW2){
      int n = i >> 9;
      int k = i & 511;
      g_w2t[(n << 9) | (k ^ ((n & 7) << 3))] = f2bf(W2[(size_t)k * MH_ + n]);
    } else if (i < NW2 + NW){
      int j = i - NW2;
      int head = j >> 16;
      int r = j & 65535;
      int pc = r >> 7, k = r & 127;
      int w = pc >> 6, g = (pc >> 4) & 3, s = pc & 15;
      int row = g*128 + w*16 + s;
      float sc = (g == 2) ? (2.0f*L2E) : (-L2E);
      g_whh[head][pc][k] = f2bf(A.Whh[head][row*H_ + k] * sc);
    } else if (i < NW2 + NW + NI){
      int j = i - NW2 - NW;
      int head = j >> 14;
      int r = j & 16383;
      int pc = r >> 5, k = r & 31;
      int w = pc >> 6, g = (pc >> 4) & 3, s = pc & 15;
      int row = g*128 + w*16 + s;
      float sc = (g == 2) ? (2.0f*L2E) : (-L2E);
      g_wih[head][pc][k] = (k < 8) ? f2bf(A.Wih[head][row*F_ + k] * sc) : (unsigned short)0;
    } else {
      int j = i - NW2 - NW - NI;
      int head = j >> 20;
      int r = j & 1048575;
      g_xbf[head][r] = f2bf(A.x[head][r]);
    }
  }
}

// MFMA LSTM — r17 verified base (215us) with ONE isolated delta:
// minimum-depth MFMA chains. x-MFMA (operand prefetched last step,
// independent of this step's ds_read) STARTS chain A during the ah
// ds_read latency; chain B zero-inits on ah[2]:
//   A: x -> ah0 -> ah1   (3-deep; first link free under ds_read)
//   B: ah2 -> ah3        (2-deep)
// vs the old single 5-deep chain exposed after the ds_read. Gate math
// stays the old PARALLEL per-gate form (r16's algebra serialized it).
__global__ __launch_bounds__(512) void lstm_mfma_kernel(LstmArgs A){
  const int head   = blockIdx.x >> 6;          // 64 tiles per head, 192 blocks
  const int batch0 = (blockIdx.x & 63) * 8;
  const int tid = threadIdx.x;
  const int w   = tid >> 6;
  const int l   = tid & 63;
  const int c16 = l & 15;
  const int kb  = (l >> 4) * 8;

  const float* __restrict__ bs  = A.bias[head];
  const float* __restrict__ hwp = A.hw[head];
  const float hbv = A.hb[head][0];
  float* __restrict__ D = A.out + (size_t)head * BT_;

  // register-resident B-fragments
  bf16x8 bh[4][4];
  bf16x8 bx[4];
  #pragma unroll
  for (int g = 0; g < 4; ++g){
    const int pc = w*64 + g*16 + c16;
    #pragma unroll
    for (int kk = 0; kk < 4; ++kk)
      bh[g][kk] = *(const bf16x8*)&g_whh[head][pc][kk*32 + kb];
    bx[g] = *(const bf16x8*)&g_wih[head][pc][kb];
  }

  const int u = w*16 + c16;
  const float bi_ = bs[u]        * (-L2E);
  const float bf_ = bs[H_+u]     * (-L2E);
  const float bg_ = bs[2*H_+u]   * (2.0f*L2E);
  const float bo_ = bs[3*H_+u]   * (-L2E);
  const float hw_u = hwp[u];

  __shared__ __align__(16) unsigned short h_bf[2][16][132];
  __shared__ float part[2][8][8];

  for (int i = tid; i < 2*16*132; i += 512) ((unsigned short*)h_bf)[i] = 0;

  float cst[2] = {0.f, 0.f};
  float pp[2]  = {0.f, 0.f};

  // x A-row mapping: lane c16 supplies A-row c16; valid rows {0,1,4,5,8,9,12,13}
  const int bt = ((c16 >> 2) << 1) | (c16 & 1);          // batch-in-tile for row c16
  const bool xvalid = (l < 16) && !(l & 2);
  const unsigned short* __restrict__ xrow =
      &g_xbf[head][(size_t)(batch0 + bt) * (T_*F_)];

  bf16x8 ax_cur = {};
  if (xvalid) ax_cur = *(const bf16x8*)(xrow);

  __syncthreads();

  int cur = 0;
  for (int ts = 0; ts < T_; ++ts){
    // A-frags for current h
    bf16x8 ah[4];
    #pragma unroll
    for (int kk = 0; kk < 4; ++kk)
      ah[kk] = *(const bf16x8*)&h_bf[cur][c16][kk*32 + kb];

    // prefetch next step's x (off the critical path; stays in flight)
    bf16x8 ax_nxt = {};
    {
      const int tn = (ts + 1 < T_) ? ts + 1 : ts;
      if (xvalid) ax_nxt = *(const bf16x8*)(xrow + tn*F_);
    }

    // minimum-depth MFMA chains:
    //   chain A (acc):  x-MFMA (indep of ds_read) -> ah0 -> ah1
    //   chain B (acc2): ah2 -> ah3
    f32x4 acc[4], acc2[4];
    const f32x4 z4 = {0.f, 0.f, 0.f, 0.f};
    #pragma unroll
    for (int g = 0; g < 4; ++g)
      acc[g]  = __builtin_amdgcn_mfma_f32_16x16x32_bf16(ax_cur, bx[g], z4, 0, 0, 0);
    #pragma unroll
    for (int g = 0; g < 4; ++g)
      acc2[g] = __builtin_amdgcn_mfma_f32_16x16x32_bf16(ah[2], bh[g][2], z4, 0, 0, 0);
    #pragma unroll
    for (int g = 0; g < 4; ++g)
      acc[g]  = __builtin_amdgcn_mfma_f32_16x16x32_bf16(ah[0], bh[g][0], acc[g], 0, 0, 0);
    #pragma unroll
    for (int g = 0; g < 4; ++g)
      acc2[g] = __builtin_amdgcn_mfma_f32_16x16x32_bf16(ah[3], bh[g][3], acc2[g], 0, 0, 0);
    #pragma unroll
    for (int g = 0; g < 4; ++g)
      acc[g]  = __builtin_amdgcn_mfma_f32_16x16x32_bf16(ah[1], bh[g][1], acc[g], 0, 0, 0);

    // previous step's head-dot reduction (DPP on VALU; overlaps MFMA)
    if (ts > 0){
      #pragma unroll
      for (int r = 0; r < 2; ++r){
        float v = pp[r];
        v = dpp_sum_step<0xB1>(v);    // ~xor1
        v = dpp_sum_step<0x4E>(v);    // ~xor2
        v = dpp_sum_step<0x141>(v);   // half-mirror (complementary quads)
        v = dpp_sum_step<0x140>(v);   // mirror (complementary octets)
        if (c16 == 0) part[(ts-1) & 1][(l >> 4)*2 + r][w] = v;
      }
    }

    // cell update: 2 cells/lane (regs r=0,1), PARALLEL exp2-form gates
    #pragma unroll
    for (int r = 0; r < 2; ++r){
      const float Zi = (acc[0][r] + acc2[0][r]) + bi_;
      const float Zf = (acc[1][r] + acc2[1][r]) + bf_;
      const float Zg = (acc[2][r] + acc2[2][r]) + bg_;
      const float Zo = (acc[3][r] + acc2[3][r]) + bo_;
      const float si = RCPF(1.f + EXP2F(Zi));
      const float sf = RCPF(1.f + EXP2F(Zf));
      const float tg = 1.f - 2.f * RCPF(EXP2F(Zg) + 1.f);
      const float so = RCPF(1.f + EXP2F(Zo));
      cst[r] = sf * cst[r] + si * tg;
      const float tc = 1.f - 2.f * RCPF(EXP2F(cst[r] * (2.0f*L2E)) + 1.f);
      const float hnr = so * tc;
      h_bf[cur ^ 1][(l >> 4)*4 + r][u] = f2bf(hnr);
      pp[r] = hnr * hw_u;                       // consumed next iteration
    }

    bar_lgkm();                                 // new h + part visible (lgkm only)

    // finalize D for step ts-1 (wave 0 only; overlaps other waves' next step)
    if (ts > 0 && tid < 64){
      const int b  = tid >> 3;
      const int wv = tid & 7;
      float v = part[(ts-1) & 1][b][wv];
      v = dpp_sum_step<0xB1>(v);
      v = dpp_sum_step<0x4E>(v);
      v = dpp_sum_step<0x141>(v);
      if (wv == 0) D[(size_t)(batch0 + b) * T_ + (ts-1)] = v + hbv;
    }

    ax_cur = ax_nxt;
    cur ^= 1;
  }

  // epilogue: step T-1's head-dot
  #pragma unroll
  for (int r = 0; r < 2; ++r){
    float v = pp[r];
    v = dpp_sum_step<0xB1>(v);
    v = dpp_sum_step<0x4E>(v);
    v = dpp_sum_step<0x141>(v);
    v = dpp_sum_step<0x140>(v);
    if (c16 == 0) part[(T_-1) & 1][(l >> 4)*2 + r][w] = v;
  }
  __syncthreads();
  if (tid < 64){
    const int b  = tid >> 3;
    const int wv = tid & 7;
    float v = part[(T_-1) & 1][b][wv];
    v = dpp_sum_step<0xB1>(v);
    v = dpp_sum_step<0x4E>(v);
    v = dpp_sum_step<0x141>(v);
    if (wv == 0) D[(size_t)(batch0 + b) * T_ + (T_-1)] = v + hbv;
  }
}

// Fused MLP v4 (r17 verified): 512 blocks x 512 threads (8 waves),
// 256 rows/block; each staged W2 pass serves 8 waves. launch_bounds(512,1):
// VGPR cap 256 (NOT (512,2): cap 128 would spill afr — r8/r9 lesson).
__global__ __launch_bounds__(512, 1) void mlp_kernel(
    const float* __restrict__ Dbase,
    const float* __restrict__ W1, const float* __restrict__ b1,
    const float* __restrict__ b2, const float* __restrict__ W3,
    const float* __restrict__ b3, float* __restrict__ out)
{
  __shared__ __align__(16) unsigned short buf[2][32*512];   // 2 x 32KB

  const int tid = threadIdx.x;
  const int l   = tid & 63;
  const int c16 = l & 15;
  const int kb  = (l >> 4) * 8;
  const int w   = tid >> 6;                 // 0..7
  const int m0  = blockIdx.x * 256 + w * 32;

  // A fragments for 2 M-tiles (computed once; live for whole kernel)
  bf16x8 afr[2][16];
  {
    float d[2][3];
    #pragma unroll
    for (int mt = 0; mt < 2; ++mt){
      const int gr = m0 + mt*16 + c16;
      d[mt][0] = Dbase[gr];
      d[mt][1] = Dbase[BT_ + gr];
      d[mt][2] = Dbase[2*BT_ + gr];
    }
    #pragma unroll
    for (int ks = 0; ks < 16; ++ks){
      const int kg = ks*32 + kb;
      const f32x4 wa0 = *(const f32x4*)(W1 + kg);          const f32x4 wa1 = *(const f32x4*)(W1 + kg + 4);
      const f32x4 wb0 = *(const f32x4*)(W1 + MH_ + kg);    const f32x4 wb1 = *(const f32x4*)(W1 + MH_ + kg + 4);
      const f32x4 wc0 = *(const f32x4*)(W1 + 2*MH_ + kg);  const f32x4 wc1 = *(const f32x4*)(W1 + 2*MH_ + kg + 4);
      const f32x4 bv0 = *(const f32x4*)(b1 + kg);          const f32x4 bv1 = *(const f32x4*)(b1 + kg + 4);
      #pragma unroll
      for (int mt = 0; mt < 2; ++mt){
        union { unsigned short us[8]; bf16x8 v; } au;
        #pragma unroll
        for (int i = 0; i < 4; ++i){
          float v0 = fmaf(d[mt][2], wc0[i], fmaf(d[mt][1], wb0[i], fmaf(d[mt][0], wa0[i], bv0[i])));
          float v1 = fmaf(d[mt][2], wc1[i], fmaf(d[mt][1], wb1[i], fmaf(d[mt][0], wa1[i], bv1[i])));
          au.us[i]     = f2bf(fmaxf(v0, 0.f));
          au.us[4 + i] = f2bf(fmaxf(v1, 0.f));
        }
        afr[mt][ks] = au.v;
      }
    }
  }

  // prologue: stage regs for pass 0 (pass = 32 cols = 2048 uint4; 4/thread)
  const uint4* __restrict__ gsrc = (const uint4*)g_w2t;
  uint4 rg0, rg1, rg2, rg3;
  {
    const uint4* s = gsrc + tid;
    rg0 = s[0*512]; rg1 = s[1*512]; rg2 = s[2*512]; rg3 = s[3*512];
  }

  float rs[2][4] = {{0.f,0.f,0.f,0.f},{0.f,0.f,0.f,0.f}};

  #pragma unroll 1
  for (int p = 0; p < 16; ++p){
    {
      uint4* bw = (uint4*)buf[p & 1] + tid;
      bw[0*512] = rg0; bw[1*512] = rg1; bw[2*512] = rg2; bw[3*512] = rg3;
    }
    __syncthreads();               // write visible; dbuf makes this the ONLY barrier
    if (p < 15){
      const uint4* s = gsrc + (p + 1) * 2048 + tid;
      rg0 = s[0*512]; rg1 = s[1*512]; rg2 = s[2*512]; rg3 = s[3*512];
    }
    float b2v[2], w3v[2];
    #pragma unroll
    for (int nt = 0; nt < 2; ++nt){
      const int n = p*32 + nt*16 + c16;
      b2v[nt] = b2[n];
      w3v[nt] = W3[n];
    }

    const unsigned short* __restrict__ bb = buf[p & 1];
    f32x4 acc[2][2];
    #pragma unroll
    for (int nt = 0; nt < 2; ++nt){
      f32x4 z = {0.f,0.f,0.f,0.f};
      acc[0][nt] = z; acc[1][nt] = z;
    }
    #pragma unroll
    for (int ks = 0; ks < 16; ++ks){
      #pragma unroll
      for (int nt = 0; nt < 2; ++nt){
        const int nl = nt*16 + c16;                    // local col 0..31
        const bf16x8 bfr =
          *(const bf16x8*)&bb[(nl << 9) | ((ks*32 + kb) ^ ((nl & 7) << 3))];
        acc[0][nt] = __builtin_amdgcn_mfma_f32_16x16x32_bf16(afr[0][ks], bfr, acc[0][nt], 0, 0, 0);
        acc[1][nt] = __builtin_amdgcn_mfma_f32_16x16x32_bf16(afr[1][ks], bfr, acc[1][nt], 0, 0, 0);
      }
    }
    #pragma unroll
    for (int nt = 0; nt < 2; ++nt){
      #pragma unroll
      for (int mt = 0; mt < 2; ++mt)
        #pragma unroll
        for (int r = 0; r < 4; ++r)
          rs[mt][r] += fmaxf(acc[mt][nt][r] + b2v[nt], 0.f) * w3v[nt];
    }
  }

  // reduce across the 16 lanes (c16 bits) sharing the same C-rows
  #pragma unroll
  for (int mt = 0; mt < 2; ++mt){
    #pragma unroll
    for (int r = 0; r < 4; ++r){
      rs[mt][r] += __shfl_xor(rs[mt][r], 1);
      rs[mt][r] += __shfl_xor(rs[mt][r], 2);
      rs[mt][r] += __shfl_xor(rs[mt][r], 4);
      rs[mt][r] += __shfl_xor(rs[mt][r], 8);
    }
  }
  if (c16 == 0){
    const float bv = b3[0];
    #pragma unroll
    for (int mt = 0; mt < 2; ++mt){
      const int row = m0 + mt*16 + (l >> 4) * 4;
      #pragma unroll
      for (int r = 0; r < 4; ++r)
        out[3*BT_ + row + r] = rs[mt][r] + bv;
    }
  }
}

extern "C" void kernel_launch(void* const* d_in, const int* in_sizes, int n_in,
                              void* d_out, int out_size, void* d_ws, size_t ws_size,
                              hipStream_t stream){
  LstmArgs A;
  for (int i = 0; i < 3; ++i){
    A.x[i]    = (const float*)d_in[i];
    A.Wih[i]  = (const float*)d_in[3 + i*5 + 0];
    A.Whh[i]  = (const float*)d_in[3 + i*5 + 1];
    A.bias[i] = (const float*)d_in[3 + i*5 + 2];
    A.hw[i]   = (const float*)d_in[3 + i*5 + 3];
    A.hb[i]   = (const float*)d_in[3 + i*5 + 4];
  }
  A.out = (float*)d_out;

  prep_all<<<dim3(2048), dim3(256), 0, stream>>>(A, (const float*)d_in[20]);
  lstm_mfma_kernel<<<dim3(192), dim3(512), 0, stream>>>(A);
  mlp_kernel<<<dim3(512), dim3(512), 0, stream>>>((const float*)d_out,
      (const float*)d_in[18], (const float*)d_in[19],
      (const float*)d_in[21], (const float*)d_in[22], (const float*)d_in[23],
      (float*)d_out);
}